// Round 5
// baseline (36715.546 us; speedup 1.0000x reference)
//
#include <hip/hip_runtime.h>
#include <hip/hip_bf16.h>

// Inputs/outputs are FLOAT32 (per reference). Compute uses bf16 MFMA.
typedef __attribute__((ext_vector_type(8))) short short8;   // 8 bf16 = 4 VGPRs (MFMA A/B frag)
typedef __attribute__((ext_vector_type(4))) float floatx4;  // MFMA C/D frag

#define TBH ((size_t)16777216)  // 32768*512 per-gate G stride (elements)

__device__ __forceinline__ float bfbits2f(unsigned short b) {
  return __uint_as_float(((unsigned int)b) << 16);
}
__device__ __forceinline__ unsigned short f2bf(float f) {
  unsigned int u = __float_as_uint(f);
  unsigned int r = (u + 0x7fffu + ((u >> 16) & 1u)) >> 16;  // RNE
  return (unsigned short)r;
}

// Relaxed agent-scope atomics (coherence point = IC; proven R2 path).
// Exchanged word = bf16 value in high 16 | step tag in low 16.
__device__ __forceinline__ void dev_store(unsigned int* p, unsigned int v) {
  __hip_atomic_store(p, v, __ATOMIC_RELAXED, __HIP_MEMORY_SCOPE_AGENT);
}
__device__ __forceinline__ unsigned int dev_load(const unsigned int* p) {
  return __hip_atomic_load(p, __ATOMIC_RELAXED, __HIP_MEMORY_SCOPE_AGENT);
}

// LDS barrier WITHOUT vmcnt(0) drain: publish stores stay in flight across
// the barrier. lgkmcnt(0) orders LDS. sched_barrier(0) per guide rule #18.
#define LBAR()                                              \
  do {                                                      \
    asm volatile("s_waitcnt lgkmcnt(0)" ::: "memory");      \
    __builtin_amdgcn_s_barrier();                           \
    __builtin_amdgcn_sched_barrier(0);                      \
  } while (0)

#define MFMA16(a, b, c) __builtin_amdgcn_mfma_f32_16x16x32_bf16((a), (b), (c), 0, 0, 0)

// -------------------------------------------------------------------------
// prep: hpub = bf16(h0)|tag0 ; rhpub = 0 ; Whr/Whi/Whn -> bf16.
// -------------------------------------------------------------------------
__global__ void prep_kernel(const float* __restrict__ h0,
                            unsigned int* __restrict__ hpub,
                            unsigned int* __restrict__ rhpub,
                            const float* __restrict__ Whr,
                            const float* __restrict__ Whi,
                            const float* __restrict__ Whn,
                            unsigned short* __restrict__ Whb) {
  int i = blockIdx.x * 256 + threadIdx.x;  // grid 1024*256 = 262144
  if (i < 64 * 512) {
    hpub[i] = ((unsigned int)f2bf(h0[i])) << 16;  // tag 0 == h_0
    rhpub[i] = 0u;                                // != first rh tag (1)
  }
#pragma unroll
  for (int rep = 0; rep < 3; ++rep) {
    int j = i + rep * 262144;
    float v = (j < 262144) ? Whr[j] : ((j < 524288) ? Whi[j - 262144] : Whn[j - 524288]);
    Whb[j] = f2bf(v);
  }
}

// -------------------------------------------------------------------------
// Phase 1: G[gate][t*64+b][n] = x@Wi^T + ctx@Wp^T + (bi+bh+bp)   (bf16 out)
// (unchanged)
// -------------------------------------------------------------------------
struct PreArgs {
  const float* x;
  const float* ctx;
  const float* Wi[3];
  const float* Wp[3];
  const float* bi[3];
  const float* bh[3];
  const float* bp[3];
  unsigned short* G;
};

__global__ __launch_bounds__(256) void gemm_pre(PreArgs args) {
  __shared__ short8 a_sm[512];  // [row(128)][sub(4)] : 128x32 bf16
  __shared__ short8 b_sm[512];
  const int tid = threadIdx.x;
  const int gate = blockIdx.z;
  const int n0 = blockIdx.x * 128;
  const int m0 = blockIdx.y * 128;
  const int wave = tid >> 6, lane = tid & 63;
  const int wm = (wave & 1) * 64, wn = (wave >> 1) * 64;
  const int lm = lane & 15, lq = lane >> 4;
  const float* Wi = args.Wi[gate];
  const float* Wp = args.Wp[gate];

  floatx4 acc[4][4];
#pragma unroll
  for (int i = 0; i < 4; ++i)
#pragma unroll
    for (int j = 0; j < 4; ++j) acc[i][j] = floatx4{0.f, 0.f, 0.f, 0.f};

  for (int kb = 0; kb < 32; ++kb) {
    const float* asrc = (kb < 16) ? args.x : args.ctx;
    const float* bsrc = (kb < 16) ? Wi : Wp;
    const int k0 = (kb & 15) * 32;
    __syncthreads();
#pragma unroll
    for (int c = 0; c < 2; ++c) {
      int s = c * 256 + tid;
      int row = s >> 2, sub = s & 3;
      const float* ap = asrc + (size_t)(m0 + row) * 512 + k0 + sub * 8;
      const float* bp = bsrc + (size_t)(n0 + row) * 512 + k0 + sub * 8;
      float4 a0 = *(const float4*)ap, a1 = *(const float4*)(ap + 4);
      float4 b0 = *(const float4*)bp, b1 = *(const float4*)(bp + 4);
      short8 av, bv;
      av[0] = (short)f2bf(a0.x); av[1] = (short)f2bf(a0.y);
      av[2] = (short)f2bf(a0.z); av[3] = (short)f2bf(a0.w);
      av[4] = (short)f2bf(a1.x); av[5] = (short)f2bf(a1.y);
      av[6] = (short)f2bf(a1.z); av[7] = (short)f2bf(a1.w);
      bv[0] = (short)f2bf(b0.x); bv[1] = (short)f2bf(b0.y);
      bv[2] = (short)f2bf(b0.z); bv[3] = (short)f2bf(b0.w);
      bv[4] = (short)f2bf(b1.x); bv[5] = (short)f2bf(b1.y);
      bv[6] = (short)f2bf(b1.z); bv[7] = (short)f2bf(b1.w);
      a_sm[row * 4 + sub] = av;
      b_sm[row * 4 + sub] = bv;
    }
    __syncthreads();
    short8 af[4], bf[4];
#pragma unroll
    for (int i = 0; i < 4; ++i) af[i] = a_sm[(wm + i * 16 + lm) * 4 + lq];
#pragma unroll
    for (int j = 0; j < 4; ++j) bf[j] = b_sm[(wn + j * 16 + lm) * 4 + lq];
#pragma unroll
    for (int i = 0; i < 4; ++i)
#pragma unroll
      for (int j = 0; j < 4; ++j)
        acc[i][j] = MFMA16(af[i], bf[j], acc[i][j]);
  }

#pragma unroll
  for (int j = 0; j < 4; ++j) {
    int n = n0 + wn + j * 16 + lm;
    float bias = args.bi[gate][n] + args.bh[gate][n] + args.bp[gate][n];
#pragma unroll
    for (int i = 0; i < 4; ++i) {
      int mbase = m0 + wm + i * 16 + lq * 4;
#pragma unroll
      for (int r = 0; r < 4; ++r) {
        int m = mbase + r;
        int t = m & 511, b = m >> 9;
        args.G[(size_t)gate * TBH + (size_t)(t * 64 + b) * 512 + n] = f2bf(acc[i][j][r] + bias);
      }
    }
  }
}

// -------------------------------------------------------------------------
// Recurrence: 4 WGs, one per 128-col slice, ALL 64 batches each (full 16-row
// MFMA tiles x4). 512 thr = 8 waves; wave owns 16 cols x all rows, weights
// for its cols in VGPRs/AGPRs (48 short8/lane, R2-proven). Two tagged
// agent-scope handoffs per step (h, r*h), fan-in 4 among only 4 WGs.
// Double-buffered frag LDS (bufH/bufR, 64KB each) -> 2 barriers per step.
// -------------------------------------------------------------------------
__global__ __launch_bounds__(512, 2) void recur_kernel(
    const unsigned short* __restrict__ G,
    const unsigned short* __restrict__ Whb,   // [3][512][512] bf16
    const float* __restrict__ h0,
    unsigned int* __restrict__ hpub,          // [64][512] bf16<<16|tag(t)
    unsigned int* __restrict__ rhpub,         // [64][512] bf16<<16|tag(t+1)
    float* __restrict__ ys,                   // [64][512][512] f32
    float* __restrict__ hT) {                 // [64][512] f32
  __shared__ short8 bufH[4096];  // [kb(16)][mt(4)][lane(64)] h A-frags: 64 KB
  __shared__ short8 bufR[4096];  // same for r*h: 64 KB

  const int tid = threadIdx.x;
  const int cb = blockIdx.x;            // col slice 0..3
  const int wave = tid >> 6, lane = tid & 63;
  const int lm = lane & 15, lq = lane >> 4;
  const int kcol = cb * 128 + wave * 16 + lm;  // own output col

  // ---- weights -> regs (48 short8/lane; compiler places in VGPR/AGPR) ----
  const unsigned short* Wb = Whb + (size_t)kcol * 512 + lq * 8;
  short8 wr[16], wi[16], wn[16];
#pragma unroll
  for (int kb = 0; kb < 16; ++kb) {
    wr[kb] = *(const short8*)(Wb + 0 * 262144 + kb * 32);
    wi[kb] = *(const short8*)(Wb + 1 * 262144 + kb * 32);
    wn[kb] = *(const short8*)(Wb + 2 * 262144 + kb * 32);
  }

  // ---- staging map: thread covers (row rr, 16 cols cg*16) of a slice ----
  const int rr = tid >> 3, cg = tid & 7;
  const int mt_s = rr >> 4, r16 = rr & 15;
  const int gpair = (cg & 1) << 1;
  int sidx[3], soff[3];
#pragma unroll
  for (int s = 0; s < 3; ++s) {
    const int rcb = (cb + 1 + s) & 3;
    sidx[s] = ((rcb * 4 + (cg >> 1)) * 4 + mt_s) * 64 + r16 + gpair * 16;
    soff[s] = rr * 512 + rcb * 128 + cg * 16;
  }
  unsigned short* fH = (unsigned short*)bufH;
  unsigned short* fR = (unsigned short*)bufR;

  // ---- own-value LDS scatter base: idx = ebase + mt*512 + r*8 ----
  const int ebase = ((kcol >> 5) * 256 + (((kcol & 31) >> 3) * 16 + lq * 4)) * 8 + (kcol & 7);
  const int pbase = (lq * 4) * 512 + kcol;  // publish base (row lq*4, col kcol)

  // ---- init: h0 -> bufH (all 4 slices) + hreg (f32, register-carried) ----
#pragma unroll
  for (int s = 0; s < 4; ++s) {
    const int rcb = (cb + s) & 3;
    const float* hp = h0 + rr * 512 + rcb * 128 + cg * 16;
    const int bidx = ((rcb * 4 + (cg >> 1)) * 4 + mt_s) * 64 + r16 + gpair * 16;
    short8 sv0, sv1;
#pragma unroll
    for (int e = 0; e < 8; ++e) {
      sv0[e] = (short)f2bf(hp[e]);
      sv1[e] = (short)f2bf(hp[8 + e]);
    }
    bufH[bidx] = sv0;
    bufH[bidx + 16] = sv1;
  }
  float hreg[16];
#pragma unroll
  for (int mt = 0; mt < 4; ++mt)
#pragma unroll
    for (int r = 0; r < 4; ++r)
      hreg[mt * 4 + r] = h0[(mt * 16 + lq * 4 + r) * 512 + kcol];
  __syncthreads();

  for (int t = 0; t < 512; ++t) {
    const unsigned int htag = (unsigned int)t;
    const unsigned int rtag = (unsigned int)(t + 1);

    // ---- G loads for step t (issued first: their HBM drain hides under
    //      the producer wait inside the h-poll) ----
    unsigned short grv[16], giv[16], gnv[16];
    {
      const unsigned short* gt = G + (size_t)t * 32768 + pbase;
#pragma unroll
      for (int mt = 0; mt < 4; ++mt)
#pragma unroll
        for (int r = 0; r < 4; ++r) {
          const int o = (mt * 16 + r) * 512;
          grv[mt * 4 + r] = gt[o];
          giv[mt * 4 + r] = gt[TBH + o];
          gnv[mt * 4 + r] = gt[2 * TBH + o];
        }
    }

    // ---- poll remote h (3 slices x 16 words), stage into bufH ----
    {
      unsigned int v[3][16];
#pragma unroll
      for (int s = 0; s < 3; ++s)
#pragma unroll
        for (int j = 0; j < 16; ++j) v[s][j] = dev_load(hpub + soff[s] + j);
      for (;;) {
        bool ok = true;
#pragma unroll
        for (int s = 0; s < 3; ++s)
#pragma unroll
          for (int j = 0; j < 16; ++j) ok &= ((v[s][j] & 0xffffu) == htag);
        if (ok) break;
#pragma unroll
        for (int s = 0; s < 3; ++s) {
          bool st = false;
#pragma unroll
          for (int j = 0; j < 16; ++j) st |= ((v[s][j] & 0xffffu) != htag);
          if (st) {
#pragma unroll
            for (int j = 0; j < 16; ++j) v[s][j] = dev_load(hpub + soff[s] + j);
          }
        }
      }
#pragma unroll
      for (int s = 0; s < 3; ++s) {
        short8 sv0, sv1;
#pragma unroll
        for (int e = 0; e < 8; ++e) {
          sv0[e] = (short)(v[s][e] >> 16);
          sv1[e] = (short)(v[s][8 + e] >> 16);
        }
        bufH[sidx[s]] = sv0;
        bufH[sidx[s] + 16] = sv1;
      }
    }
    LBAR();  // (1) bufH complete (all waves' own h already staged last step)

    // ---- r,i MFMAs: 4 mtiles x 16 kb, A-frag read once, used twice ----
    floatx4 ar[4], ai[4];
#pragma unroll
    for (int mt = 0; mt < 4; ++mt) {
      ar[mt] = floatx4{0.f, 0.f, 0.f, 0.f};
      ai[mt] = floatx4{0.f, 0.f, 0.f, 0.f};
    }
#pragma unroll
    for (int kb = 0; kb < 16; ++kb)
#pragma unroll
      for (int mt = 0; mt < 4; ++mt) {
        short8 a = bufH[(kb * 4 + mt) * 64 + lane];
        ar[mt] = MFMA16(a, wr[kb], ar[mt]);
        ai[mt] = MFMA16(a, wi[kb], ai[mt]);
      }

    // ---- epilogue A: r sigmoid, publish rh ASAP, stage own rh ----
    unsigned int* rpb = rhpub + pbase;
#pragma unroll
    for (int mt = 0; mt < 4; ++mt)
#pragma unroll
      for (int r = 0; r < 4; ++r) {
        float rsum = ar[mt][r] + bfbits2f(grv[mt * 4 + r]);
        float rv = 1.f / (1.f + __expf(-rsum));
        unsigned short rb = f2bf(rv * hreg[mt * 4 + r]);
        dev_store(rpb + mt * 8192 + r * 512, (((unsigned int)rb) << 16) | rtag);
        fR[ebase + mt * 512 + r * 8] = rb;
      }

    // ---- poll remote rh; i-sigmoids computed while loads fly ----
    float ireg[16];
    {
      unsigned int v[3][16];
#pragma unroll
      for (int s = 0; s < 3; ++s)
#pragma unroll
        for (int j = 0; j < 16; ++j) v[s][j] = dev_load(rhpub + soff[s] + j);
#pragma unroll
      for (int k = 0; k < 16; ++k)
        ireg[k] = 1.f / (1.f + __expf(-(ai[k >> 2][k & 3] + bfbits2f(giv[k]))));
      for (;;) {
        bool ok = true;
#pragma unroll
        for (int s = 0; s < 3; ++s)
#pragma unroll
          for (int j = 0; j < 16; ++j) ok &= ((v[s][j] & 0xffffu) == rtag);
        if (ok) break;
#pragma unroll
        for (int s = 0; s < 3; ++s) {
          bool st = false;
#pragma unroll
          for (int j = 0; j < 16; ++j) st |= ((v[s][j] & 0xffffu) != rtag);
          if (st) {
#pragma unroll
            for (int j = 0; j < 16; ++j) v[s][j] = dev_load(rhpub + soff[s] + j);
          }
        }
      }
#pragma unroll
      for (int s = 0; s < 3; ++s) {
        short8 sv0, sv1;
#pragma unroll
        for (int e = 0; e < 8; ++e) {
          sv0[e] = (short)(v[s][e] >> 16);
          sv1[e] = (short)(v[s][8 + e] >> 16);
        }
        bufR[sidx[s]] = sv0;
        bufR[sidx[s] + 16] = sv1;
      }
    }
    LBAR();  // (2) bufR complete; also: all phase-A bufH reads done

    // ---- n MFMA ----
    floatx4 an[4];
#pragma unroll
    for (int mt = 0; mt < 4; ++mt) an[mt] = floatx4{0.f, 0.f, 0.f, 0.f};
#pragma unroll
    for (int kb = 0; kb < 16; ++kb)
#pragma unroll
      for (int mt = 0; mt < 4; ++mt)
        an[mt] = MFMA16(bufR[(kb * 4 + mt) * 64 + lane], wn[kb], an[mt]);

    // ---- epilogue B: tanh, blend, publish h(t+1) ASAP, stage own h, ys ----
    unsigned int* hpb = hpub + pbase;
    float hyv[16];
#pragma unroll
    for (int mt = 0; mt < 4; ++mt)
#pragma unroll
      for (int r = 0; r < 4; ++r) {
        const int k = mt * 4 + r;
        float pre = an[mt][r] + bfbits2f(gnv[k]);
        float e = __expf(2.f * pre);
        float nv = 1.f - 2.f / (e + 1.f);  // tanh
        float hy = (1.f - ireg[k]) * hreg[k] + ireg[k] * nv;
        hreg[k] = hy;
        hyv[k] = hy;
        unsigned short hb = f2bf(hy);
        dev_store(hpb + mt * 8192 + r * 512, (((unsigned int)hb) << 16) | rtag);
        fH[ebase + mt * 512 + r * 8] = hb;
      }
#pragma unroll
    for (int mt = 0; mt < 4; ++mt)
#pragma unroll
      for (int r = 0; r < 4; ++r)
        ys[(size_t)(mt * 16 + lq * 4 + r) * 262144 + (size_t)t * 512 + kcol] = hyv[mt * 4 + r];
    if (t == 511) {
#pragma unroll
      for (int mt = 0; mt < 4; ++mt)
#pragma unroll
        for (int r = 0; r < 4; ++r)
          hT[(size_t)(mt * 16 + lq * 4 + r) * 512 + kcol] = hreg[mt * 4 + r];
    }
    // no end-of-step barrier: next step's LBAR(1) orders own-h LDS writes,
    // and buffer disjointness (bufH remote regions vs bufR reads) covers
    // the cross-wave overlap window.
  }
}

// -------------------------------------------------------------------------
extern "C" void kernel_launch(void* const* d_in, const int* in_sizes, int n_in,
                              void* d_out, int out_size, void* d_ws, size_t ws_size,
                              hipStream_t stream) {
  typedef const float* cfp;
  cfp x = (cfp)d_in[0];
  cfp h0 = (cfp)d_in[1];
  cfp ctx = (cfp)d_in[2];

  PreArgs pa;
  pa.x = x;
  pa.ctx = ctx;
  for (int gi = 0; gi < 3; ++gi) {
    pa.Wi[gi] = (cfp)d_in[3 + 6 * gi];
    pa.bi[gi] = (cfp)d_in[4 + 6 * gi];
    pa.bh[gi] = (cfp)d_in[6 + 6 * gi];
    pa.Wp[gi] = (cfp)d_in[7 + 6 * gi];
    pa.bp[gi] = (cfp)d_in[8 + 6 * gi];
  }
  cfp Whr = (cfp)d_in[5], Whi = (cfp)d_in[11], Whn = (cfp)d_in[17];

  char* ws = (char*)d_ws;
  unsigned short* G = (unsigned short*)ws;          // 3 gates x 32 MB bf16
  size_t off = (size_t)3 * TBH * 2;                 // 100,663,296 B
  unsigned short* Whb = (unsigned short*)(ws + off);
  off += (size_t)3 * 262144 * 2;                    // 1,572,864 B
  unsigned int* hpub = (unsigned int*)(ws + off);
  off += (size_t)64 * 512 * 4;
  unsigned int* rhpub = (unsigned int*)(ws + off);
  off += (size_t)64 * 512 * 4;
  pa.G = G;

  float* out = (float*)d_out;
  float* ys = out;
  float* hT = out + (size_t)64 * 512 * 512;

  prep_kernel<<<1024, 256, 0, stream>>>(h0, hpub, rhpub, Whr, Whi, Whn, Whb);
  dim3 gp(4, 256, 3);
  gemm_pre<<<gp, 256, 0, stream>>>(pa);
  recur_kernel<<<4, 512, 0, stream>>>(G, Whb, h0, hpub, rhpub, ys, hT);
}